// Round 9
// baseline (421.923 us; speedup 1.0000x reference)
//
#include <hip/hip_runtime.h>
#include <hip/hip_cooperative_groups.h>
namespace cg = cooperative_groups;

#define EPSLN 1e-5f

typedef short bf16x8 __attribute__((ext_vector_type(8)));
typedef float f32x4 __attribute__((ext_vector_type(4)));
typedef unsigned short u16;
typedef unsigned short u16x8 __attribute__((ext_vector_type(8)));

__device__ __forceinline__ float wsum(float v){
  #pragma unroll
  for(int o=32;o;o>>=1) v += __shfl_xor(v,o);
  return v;
}
__device__ __forceinline__ float wmax(float v){
  #pragma unroll
  for(int o=32;o;o>>=1) v = fmaxf(v,__shfl_xor(v,o));
  return v;
}
__device__ __forceinline__ u16 f2bf(float f){
  unsigned int u = __float_as_uint(f);
  u = (u + 0x7FFFu + ((u>>16)&1u)) >> 16;
  return (u16)u;
}
__device__ __forceinline__ float bf2f(u16 h){
  return __uint_as_float(((unsigned int)h)<<16);
}

struct Prm {
  const float *xin,*pxp,*sw,*bs,*tau,*temp,*om,*W2,*bp,*lnw,*lnb,*alpha,*beta,*gam,*theta,*cw;
  float *outp,*xpo;
  float *xe,*xa,*Sv,*SSv,*er2,*mask,*cc,*G;
  u16 *xvb,*xpB,*w2B,*xinb,*phi,*plo;
};

// ---------------- Phase A: row stats + bf16 copies + hi/lo split + W2 pack ----------------
__device__ __forceinline__ void phaseA(int bid, int tid, const Prm& p){
  int rl = tid>>3, q = tid&7;
  int row = bid*32 + rl;
  const float4* xr = (const float4*)(p.xin + row*64 + q*8);
  const float4* pr = (const float4*)(p.pxp + row*64 + q*8);
  float s1=0.f,s2=0.f,s3=0.f,s4=0.f;
  u16x8 xb, ph, pl;
  #pragma unroll
  for(int k=0;k<2;k++){
    float4 xv = xr[k];
    float4 pv = pr[k];
    s1 += xv.x+xv.y+xv.z+xv.w;
    s2 += fabsf(xv.x)+fabsf(xv.y)+fabsf(xv.z)+fabsf(xv.w);
    s3 += pv.x+pv.y+pv.z+pv.w;
    s4 += pv.x*pv.x+pv.y*pv.y+pv.z*pv.z+pv.w*pv.w;
    int o = k*4;
    xb[o+0]=f2bf(xv.x); xb[o+1]=f2bf(xv.y); xb[o+2]=f2bf(xv.z); xb[o+3]=f2bf(xv.w);
    u16 h0=f2bf(pv.x), h1=f2bf(pv.y), h2=f2bf(pv.z), h3=f2bf(pv.w);
    ph[o+0]=h0; ph[o+1]=h1; ph[o+2]=h2; ph[o+3]=h3;
    pl[o+0]=f2bf(pv.x-bf2f(h0)); pl[o+1]=f2bf(pv.y-bf2f(h1));
    pl[o+2]=f2bf(pv.z-bf2f(h2)); pl[o+3]=f2bf(pv.w-bf2f(h3));
  }
  *(u16x8*)(p.xinb + row*64 + q*8) = xb;
  *(u16x8*)(p.phi  + row*64 + q*8) = ph;
  *(u16x8*)(p.plo  + row*64 + q*8) = pl;
  s1 += __shfl_xor(s1,1); s1 += __shfl_xor(s1,2); s1 += __shfl_xor(s1,4);
  s2 += __shfl_xor(s2,1); s2 += __shfl_xor(s2,2); s2 += __shfl_xor(s2,4);
  s3 += __shfl_xor(s3,1); s3 += __shfl_xor(s3,2); s3 += __shfl_xor(s3,4);
  s4 += __shfl_xor(s4,1); s4 += __shfl_xor(s4,2); s4 += __shfl_xor(s4,4);
  if(q==0){ p.xe[row]=s1*(1.f/64.f); p.xa[row]=s2*(1.f/64.f); p.Sv[row]=s3; p.SSv[row]=s4; }
  if(bid<16){
    int j = bid;
    for(int idx=tid; idx<4096; idx+=256){
      int f = idx>>6, o = idx&63;
      float v = p.W2[j*4096 + idx];
      int ks = f>>5, kb = (f>>3)&3, i = f&7;
      int nt = o>>4, col = o&15;
      int ln = kb*16 + col;
      p.w2B[((j*2+ks)*4 + nt)*512 + ln*8 + i] = f2bf(v);
    }
  }
}

// ---------------- Phase B: spline/er2, edge energies, mask, cc ----------------
__device__ __forceinline__ void phaseB(int bi, int tid, unsigned char* shm, const Prm& p){
  float* swL = (float*)shm;          // 1072 f32
  float* bsL = swL + 1072;
  float* omL = bsL + 16;
  float* red = omL + 16;
  float* redE= red + 4;              // [16*4]
  int i = bi & 15;
  int w = tid>>6, lane = tid&63;
  for(int k=tid;k<16*67;k+=256) swL[k] = p.sw[i*16*67 + k];
  if(tid<16){ bsL[tid]=p.bs[i*16+tid]; omL[tid]=fabsf(p.om[i*16+tid]); }
  float v = p.xe[bi*256+tid];
  float m = wmax(fabsf(v));
  if(lane==0) red[w]=m;
  __syncthreads();
  m = fmaxf(fmaxf(red[0],red[1]),fmaxf(red[2],red[3]));
  float xn = v/(m+1e-8f);
  xn = fminf(fmaxf(xn,-0.99f),0.99f);
  float sil = xn/(1.f+expf(-xn));
  float vv = (xn+1.f)*33.f;
  int c0 = (int)floorf(vv)-1;
  float acc[16];
  #pragma unroll
  for(int j=0;j<16;j++) acc[j]=0.f;
  #pragma unroll
  for(int k=0;k<4;k++){
    int c = c0+k;
    if(c<0||c>66) continue;
    float d = fabsf(vv-(float)c);
    float bas = d<1.f ? (2.f/3.f - d*d + d*d*d*0.5f)
              : (d<2.f ? (2.f-d)*(2.f-d)*(2.f-d)*(1.f/6.f) : 0.f);
    #pragma unroll
    for(int j=0;j<16;j++) acc[j] += bas*swL[j*67+c];
  }
  float xav = p.xa[bi*256+tid];
  #pragma unroll
  for(int j=0;j<16;j++){
    float ev = sil*bsL[j] + acc[j] + omL[j];
    p.er2[(bi*16+j)*256+tid] = ev;
    float pe = wsum(fabsf(ev)*xav);
    if(lane==0) redE[j*4+w]=pe;
  }
  __syncthreads();
  if(tid<16){
    float e = (redE[tid*4+0]+redE[tid*4+1]+redE[tid*4+2]+redE[tid*4+3])*(1.f/256.f);
    float tv = fabsf(p.temp[0])+1e-4f;
    float ta = fabsf(p.tau[i*16+tid]);
    float mk = 1.f/(1.f+expf(-(e-ta)/tv));
    p.mask[bi*16+tid]=mk;
    p.cc[bi*16+tid]= e/(ta+1e-8f)*mk;
  }
}

// ---------------- Phase E2: gram G via split-bf16 MFMA ----------------
__device__ __forceinline__ void phaseE2(int e, int tid, unsigned char* shm, const Prm& p){
  u16* AfB = (u16*)shm;           // [2][4][2][64][8] u16 = 16KB
  u16* BfB = AfB + 8192;
  int b = e&7, m = (e>>3)&7, sx = (e>>6)&3, ty = e>>8;  // b lowest -> XCD=b
  int bm = b*8+m;
  int s0 = sx*64, t0 = ty*64;
  int row = tid>>2, dseg = tid&3;
  size_t offA = ((size_t)(b*16+m  )*256 + s0 + row)*64 + dseg*16;
  size_t offB = ((size_t)(b*16+m+8)*256 + t0 + row)*64 + dseg*16;
  int d0 = dseg*16;
  int ks0 = d0>>5, kb0 = (d0>>3)&3;
  int ks1 = (d0+8)>>5, kb1 = ((d0+8)>>3)&3;
  int lr = row&15, stile = row>>4;
  #define AOFF(h,stl,ks,ln) (((((h)*4+(stl))*2+(ks))*64 + (ln))*8)
  {
    uint4 v0 = *(const uint4*)(p.phi + offA);
    uint4 v1 = *(const uint4*)(p.phi + offA + 8);
    *(uint4*)(AfB + AOFF(0,stile,ks0,kb0*16+lr)) = v0;
    *(uint4*)(AfB + AOFF(0,stile,ks1,kb1*16+lr)) = v1;
    uint4 w0 = *(const uint4*)(p.plo + offA);
    uint4 w1 = *(const uint4*)(p.plo + offA + 8);
    *(uint4*)(AfB + AOFF(1,stile,ks0,kb0*16+lr)) = w0;
    *(uint4*)(AfB + AOFF(1,stile,ks1,kb1*16+lr)) = w1;
    uint4 x0 = *(const uint4*)(p.phi + offB);
    uint4 x1 = *(const uint4*)(p.phi + offB + 8);
    *(uint4*)(BfB + AOFF(0,stile,ks0,kb0*16+lr)) = x0;
    *(uint4*)(BfB + AOFF(0,stile,ks1,kb1*16+lr)) = x1;
    uint4 y0 = *(const uint4*)(p.plo + offB);
    uint4 y1 = *(const uint4*)(p.plo + offB + 8);
    *(uint4*)(BfB + AOFF(1,stile,ks0,kb0*16+lr)) = y0;
    *(uint4*)(BfB + AOFF(1,stile,ks1,kb1*16+lr)) = y1;
  }
  __syncthreads();
  int w = tid>>6, lane = tid&63;
  bf16x8 ah0 = *(const bf16x8*)(AfB + AOFF(0,w,0,lane));
  bf16x8 ah1 = *(const bf16x8*)(AfB + AOFF(0,w,1,lane));
  bf16x8 al0 = *(const bf16x8*)(AfB + AOFF(1,w,0,lane));
  bf16x8 al1 = *(const bf16x8*)(AfB + AOFF(1,w,1,lane));
  f32x4 acc[4];
  #pragma unroll
  for(int tt=0;tt<4;tt++) acc[tt] = (f32x4){0.f,0.f,0.f,0.f};
  #pragma unroll
  for(int tt=0;tt<4;tt++){
    bf16x8 bh0 = *(const bf16x8*)(BfB + AOFF(0,tt,0,lane));
    bf16x8 bh1 = *(const bf16x8*)(BfB + AOFF(0,tt,1,lane));
    bf16x8 bl0 = *(const bf16x8*)(BfB + AOFF(1,tt,0,lane));
    bf16x8 bl1 = *(const bf16x8*)(BfB + AOFF(1,tt,1,lane));
    acc[tt] = __builtin_amdgcn_mfma_f32_16x16x32_bf16(ah0, bh0, acc[tt], 0,0,0);
    acc[tt] = __builtin_amdgcn_mfma_f32_16x16x32_bf16(ah1, bh1, acc[tt], 0,0,0);
    acc[tt] = __builtin_amdgcn_mfma_f32_16x16x32_bf16(ah0, bl0, acc[tt], 0,0,0);
    acc[tt] = __builtin_amdgcn_mfma_f32_16x16x32_bf16(ah1, bl1, acc[tt], 0,0,0);
    acc[tt] = __builtin_amdgcn_mfma_f32_16x16x32_bf16(al0, bh0, acc[tt], 0,0,0);
    acc[tt] = __builtin_amdgcn_mfma_f32_16x16x32_bf16(al1, bh1, acc[tt], 0,0,0);
  }
  int col = lane&15, r4 = lane>>4;
  #pragma unroll
  for(int tt=0;tt<4;tt++){
    #pragma unroll
    for(int r=0;r<4;r++){
      p.G[((size_t)bm*256 + s0 + w*16 + r4*4 + r)*256 + t0 + tt*16 + col] = acc[tt][r];
    }
  }
  #undef AOFF
  __syncthreads();   // all LDS reads done before any reuse
}

// ---------------- Phase D: masked mean, LN, W2 MFMA, emit xp/xpB/xvb ----------------
__device__ __forceinline__ void phaseD(int b, int j, int st, int tid,
                                       unsigned char* shm, const Prm& p){
  int w = tid>>6, lane = tid&63;
  u16* xnS = (u16*)shm;              // 2KB bf16 XOR-swizzled
  float* mcL = (float*)(shm + 2048);
  __syncthreads();                   // protect LDS reuse from previous call
  if(tid<16) mcL[tid]=p.mask[(b*16+tid)*16+j];
  __syncthreads();
  float lw = p.lnw[j*64+lane], lb = p.lnb[j*64+lane];
  int bj = b*16+j;
  unsigned char* xnB = (unsigned char*)xnS;
  #pragma unroll
  for(int ri=0;ri<4;ri++){
    int sl = w*4 + ri;
    int s = st*16 + sl;
    float acc=0.f;
    #pragma unroll
    for(int i=0;i<16;i++){
      acc += p.er2[((b*16+i)*16+j)*256+s]*mcL[i]*bf2f(p.xinb[((b*16+i)*256+s)*64+lane]);
    }
    float xval = acc*(1.f/16.f);
    p.xvb[((size_t)bj*256+s)*64+lane]=f2bf(xval);
    float mu = wsum(xval)*(1.f/64.f);
    float dv = xval-mu;
    float var = wsum(dv*dv)*(1.f/64.f);
    float xnv = dv*rsqrtf(var+EPSLN)*lw + lb;
    *(u16*)(xnB + ((sl*128 + lane*2) ^ ((sl&7)<<4))) = f2bf(xnv);
  }
  __syncthreads();
  f32x4 acc = {0.f,0.f,0.f,0.f};
  int m = lane&15, kb = lane>>4;
  #pragma unroll
  for(int ks=0;ks<2;ks++){
    bf16x8 a = *(const bf16x8*)(xnB + ((m*128 + ks*64 + kb*16) ^ ((m&7)<<4)));
    bf16x8 bfr = *(const bf16x8*)(p.w2B + ((j*2+ks)*4 + w)*512 + lane*8);
    acc = __builtin_amdgcn_mfma_f32_16x16x32_bf16(a, bfr, acc, 0, 0, 0);
  }
  int f = w*16 + m;
  u16 pk[4];
  #pragma unroll
  for(int r=0;r<4;r++){
    int si = kb*4 + r;
    int s = st*16 + si;
    float xpr = acc[r] + p.bp[((size_t)j*256+s)*64+f];
    p.xpo[((size_t)bj*256+s)*64+f] = xpr;
    pk[r] = f2bf(xpr);
  }
  int s0 = st*16 + kb*4;
  int flat = ((s0>>5)*4 + w)*512 + ((s0>>3)&3)*128 + m*8 + (s0&7);
  *(ushort4*)(p.xpB + (size_t)bj*16384 + flat) = *(ushort4*)pk;
}

// ---------------- Phase F: LN stats, logits (defer-max softmax), MFMA AV, conv, residuals ----------------
__device__ __forceinline__ void phaseF(int b, int jp, int st, int tid,
                                       unsigned char* shm, const Prm& p){
  int j0 = jp*2, j1 = j0+1;
  int w = tid>>6, lane = tid&63;
  unsigned char* prB0 = shm;
  unsigned char* prB1 = shm + 8192;
  float* xpT = (float*)shm;                        // [2][3][16][68] overlay
  float* mKL = (float*)(shm + 26112);              // [2][256]
  float* rKL = (float*)(shm + 28160);
  float* mQL = (float*)(shm + 30208);
  float* rQL = (float*)(shm + 32256);
  float tv = fabsf(p.temp[0])+1e-4f;
  float inv = 1.f/(sqrtf(512.f)*tv);
  {
    int t = tid;
    float sk0=0,ssk0=0,sq0=0,ssq0=0,sk1=0,ssk1=0,sq1=0,ssq1=0;
    #pragma unroll
    for(int m=0;m<8;m++){
      float ck0 = p.cc[(b*16+m)*16+j0], cq0 = p.cc[(b*16+m+8)*16+j0];
      float ck1 = p.cc[(b*16+m)*16+j1], cq1 = p.cc[(b*16+m+8)*16+j1];
      float svk = p.Sv [(b*16+m)*256+t];
      float ssvk= p.SSv[(b*16+m)*256+t];
      float svq = p.Sv [(b*16+m+8)*256+t];
      float ssvq= p.SSv[(b*16+m+8)*256+t];
      sk0 += ck0*svk;  ssk0 += ck0*ck0*ssvk;
      sq0 += cq0*svq;  ssq0 += cq0*cq0*ssvq;
      sk1 += ck1*svk;  ssk1 += ck1*ck1*ssvk;
      sq1 += cq1*svq;  ssq1 += cq1*cq1*ssvq;
    }
    float mk0 = sk0*(1.f/512.f), mk1 = sk1*(1.f/512.f);
    float mq0 = sq0*(1.f/512.f), mq1 = sq1*(1.f/512.f);
    mKL[t]    =mk0; rKL[t]    =rsqrtf(ssk0*(1.f/512.f)-mk0*mk0+EPSLN);
    mKL[256+t]=mk1; rKL[256+t]=rsqrtf(ssk1*(1.f/512.f)-mk1*mk1+EPSLN);
    mQL[t]    =mq0; rQL[t]    =rsqrtf(ssq0*(1.f/512.f)-mq0*mq0+EPSLN);
    mQL[256+t]=mq1; rQL[256+t]=rsqrtf(ssq1*(1.f/512.f)-mq1*mq1+EPSLN);
  }
  float aM0[8], aM1[8];
  #pragma unroll
  for(int m=0;m<8;m++){
    aM0[m]=p.cc[(b*16+m)*16+j0]*p.cc[(b*16+m+8)*16+j0];
    aM1[m]=p.cc[(b*16+m)*16+j1]*p.cc[(b*16+m+8)*16+j1];
  }
  __syncthreads();
  int bj0 = b*16+j0, bj1 = b*16+j1;
  const float* Gb = p.G + (size_t)(b*8)*65536;
  float4 mQ40 = *(const float4*)&mQL[lane*4];
  float4 rQ40 = *(const float4*)&rQL[lane*4];
  float4 mQ41 = *(const float4*)&mQL[256+lane*4];
  float4 rQ41 = *(const float4*)&rQL[256+lane*4];
  #pragma unroll
  for(int q=0;q<4;q++){
    int si = w*4+q;
    int s = st*16 + si;
    f32x4 dot0 = {0.f,0.f,0.f,0.f}, dot1 = {0.f,0.f,0.f,0.f};
    #pragma unroll
    for(int m=0;m<8;m++){
      f32x4 g4 = *(const f32x4*)(Gb + (size_t)m*65536 + s*256 + lane*4);
      dot0 += aM0[m]*g4;
      dot1 += aM1[m]*g4;
    }
    // defer-max: |raw| <= sqrt(512)/tv ~ 22.6 (Cauchy-Schwarz, LN rows) -> exp safe
    {
      float mKs = 512.f*mKL[s], rKs = rKL[s];
      float e0 = expf((dot0[0] - mKs*mQ40.x)*rKs*rQ40.x*inv);
      float e1 = expf((dot0[1] - mKs*mQ40.y)*rKs*rQ40.y*inv);
      float e2 = expf((dot0[2] - mKs*mQ40.z)*rKs*rQ40.z*inv);
      float e3 = expf((dot0[3] - mKs*mQ40.w)*rKs*rQ40.w*inv);
      float isf = 1.f/wsum(e0+e1+e2+e3);
      u16 pk[4] = {f2bf(e0*isf), f2bf(e1*isf), f2bf(e2*isf), f2bf(e3*isf)};
      *(ushort4*)(prB0 + ((si*512 + lane*8) ^ ((si&7)<<4))) = *(ushort4*)pk;
    }
    {
      float mKs = 512.f*mKL[256+s], rKs = rKL[256+s];
      float e0 = expf((dot1[0] - mKs*mQ41.x)*rKs*rQ41.x*inv);
      float e1 = expf((dot1[1] - mKs*mQ41.y)*rKs*rQ41.y*inv);
      float e2 = expf((dot1[2] - mKs*mQ41.z)*rKs*rQ41.z*inv);
      float e3 = expf((dot1[3] - mKs*mQ41.w)*rKs*rQ41.w*inv);
      float isf = 1.f/wsum(e0+e1+e2+e3);
      u16 pk[4] = {f2bf(e0*isf), f2bf(e1*isf), f2bf(e2*isf), f2bf(e3*isf)};
      *(ushort4*)(prB1 + ((si*512 + lane*8) ^ ((si&7)<<4))) = *(ushort4*)pk;
    }
  }
  __syncthreads();
  int m_ = lane&15, kb = lane>>4;
  f32x4 acc0 = {0.f,0.f,0.f,0.f}, acc1 = {0.f,0.f,0.f,0.f};
  const u16* xpB0 = p.xpB + (size_t)bj0*16384;
  const u16* xpB1 = p.xpB + (size_t)bj1*16384;
  #pragma unroll
  for(int ks=0;ks<8;ks++){
    int aoff = (m_*512 + ks*64 + kb*16) ^ ((m_&7)<<4);
    int boff = ((ks*4 + w)*64 + lane)*8;
    bf16x8 a0 = *(const bf16x8*)(prB0 + aoff);
    bf16x8 a1 = *(const bf16x8*)(prB1 + aoff);
    acc0 = __builtin_amdgcn_mfma_f32_16x16x32_bf16(a0, *(const bf16x8*)(xpB0 + boff), acc0, 0,0,0);
    acc1 = __builtin_amdgcn_mfma_f32_16x16x32_bf16(a1, *(const bf16x8*)(xpB1 + boff), acc1, 0,0,0);
  }
  __syncthreads();   // prB reads done; overlay xpT
  for(int idx4 = tid; idx4 < 1536; idx4 += 256){
    int jj = idx4 / 768;
    int rem = idx4 - jj*768;
    int rr_i = rem >> 8;
    int pos = rem & 255;
    int ci = pos>>4, f4 = pos&15;
    int grow = st - 1 + rr_i;
    float4 v = {0.f,0.f,0.f,0.f};
    if(grow>=0 && grow<16){
      v = *(const float4*)(p.xpo + ((size_t)(b*16+j0+jj)*256 + grow*16 + ci)*64 + f4*4);
    }
    *(float4*)(xpT + ((jj*3+rr_i)*16+ci)*68 + f4*4) = v;
  }
  __syncthreads();
  int f = w*16 + m_;
  #pragma unroll
  for(int jj=0;jj<2;jj++){
    int j = j0+jj;
    int bj = b*16+j;
    f32x4 acc = jj ? acc1 : acc0;
    float al = fabsf(p.alpha[j]), be=fabsf(p.beta[j]), th=fabsf(p.theta[j]), ga=p.gam[j];
    const float* wq = p.cw + (j*64+f)*9;
    float w0=wq[0],w1=wq[1],w2=wq[2],w3v=wq[3],w4=wq[4],w5=wq[5],w6=wq[6],w7=wq[7],w8=wq[8];
    #pragma unroll
    for(int r=0;r<4;r++){
      int si = kb*4 + r;
      int s = st*16 + si;
      float gl = acc[r];
      float cv=0.f;
      #pragma unroll
      for(int dr=0;dr<3;dr++){
        float kw0 = dr==0?w0:(dr==1?w3v:w6);
        float kw1 = dr==0?w1:(dr==1?w4:w7);
        float kw2 = dr==0?w2:(dr==1?w5:w8);
        const float* rowp = xpT + ((jj*3+dr)*16)*68;
        if(si>0)  cv += rowp[(si-1)*68+f]*kw0;
                  cv += rowp[(si  )*68+f]*kw1;
        if(si<15) cv += rowp[(si+1)*68+f]*kw2;
      }
      float diag = xpT[((jj*3+1)*16+si)*68+f];
      size_t gi = ((size_t)bj*256+s)*64+f;
      p.outp[gi] = be*gl + al*diag + th*cv + ga*bf2f(p.xvb[gi]);
    }
  }
}

// ---------------- Cooperative mega-kernel: all phases, grid 1024x256 ----------------
__global__ void __launch_bounds__(256,4) mega(Prm p){
  __shared__ __align__(16) unsigned char shm[34304];
  cg::grid_group grid = cg::this_grid();
  int bid = blockIdx.x, tid = threadIdx.x;

  phaseA(bid, tid, p);
  grid.sync();

  phaseE2(bid, tid, shm, p);
  if(bid < 128) phaseB(bid, tid, shm, p);
  grid.sync();

  {
    int b = bid&7, j = (bid>>3)&15, st0 = bid>>7;
    phaseD(b, j, st0,     tid, shm, p);
    phaseD(b, j, st0 + 8, tid, shm, p);
  }
  grid.sync();

  {
    int b = bid&7, jp = (bid>>3)&7, st = bid>>6;
    phaseF(b, jp, st, tid, shm, p);
  }
}

// ---------------- Fallback (non-cooperative) kernels ----------------
__global__ void __launch_bounds__(256) kA_k(Prm p){
  phaseA(blockIdx.x, threadIdx.x, p);
}
__global__ void __launch_bounds__(256) kBE_k(Prm p){
  __shared__ __align__(16) unsigned char shm[32768];
  if(blockIdx.x < 128) phaseB(blockIdx.x, threadIdx.x, shm, p);
  else                 phaseE2(blockIdx.x - 128, threadIdx.x, shm, p);
}
__global__ void __launch_bounds__(256) kD_k(Prm p){
  __shared__ __align__(16) unsigned char shm[2112];
  phaseD(blockIdx.x, blockIdx.y, blockIdx.z, threadIdx.x, shm, p);
}
__global__ void __launch_bounds__(256) kF_k(Prm p){
  __shared__ __align__(16) unsigned char shm[34304];
  phaseF(blockIdx.x, blockIdx.y, blockIdx.z, threadIdx.x, shm, p);
}

extern "C" void kernel_launch(void* const* d_in, const int* in_sizes, int n_in,
                              void* d_out, int out_size, void* d_ws, size_t ws_size,
                              hipStream_t stream) {
  Prm p;
  p.xin  = (const float*)d_in[0];
  p.pxp  = (const float*)d_in[1];
  p.sw   = (const float*)d_in[2];
  p.bs   = (const float*)d_in[3];
  p.tau  = (const float*)d_in[4];
  p.temp = (const float*)d_in[5];
  p.om   = (const float*)d_in[6];
  p.W2   = (const float*)d_in[7];
  p.bp   = (const float*)d_in[8];
  p.lnw  = (const float*)d_in[9];
  p.lnb  = (const float*)d_in[10];
  p.alpha= (const float*)d_in[11];
  p.beta = (const float*)d_in[12];
  p.gam  = (const float*)d_in[13];
  p.theta= (const float*)d_in[14];
  p.cw   = (const float*)d_in[15];
  p.outp = (float*)d_out;
  p.xpo  = p.outp + 2097152;

  float* ws = (float*)d_ws;
  p.xe  = ws;                 // 32768
  p.xa  = p.xe + 32768;       // 32768
  p.Sv  = p.xa + 32768;       // 32768
  p.SSv = p.Sv + 32768;       // 32768
  p.er2 = p.SSv + 32768;      // 524288
  p.mask= p.er2 + 524288;     // 2048
  p.cc  = p.mask + 2048;      // 2048
  p.G   = p.cc + 2048;        // 4194304
  p.xvb = (u16*)(p.G + 4194304);  // 2097152 u16
  p.xpB = p.xvb + 2097152;        // 2097152 u16
  p.w2B = p.xpB + 2097152;        // 65536 u16
  p.xinb= p.w2B + 65536;          // 2097152 u16
  p.phi = p.xinb + 2097152;       // 2097152 u16
  p.plo = p.phi + 2097152;        // 2097152 u16

  void* kargs[] = { (void*)&p };
  hipError_t err = hipLaunchCooperativeKernel((const void*)mega, dim3(1024), dim3(256),
                                              kargs, 0, stream);
  if(err != hipSuccess){
    (void)hipGetLastError();   // clear sticky error, take the 4-kernel path
    kA_k <<<1024,            256, 0, stream>>>(p);
    kBE_k<<<1152,            256, 0, stream>>>(p);
    kD_k <<<dim3(8,16,16),   256, 0, stream>>>(p);
    kF_k <<<dim3(8,8,16),    256, 0, stream>>>(p);
  }
}

// Round 10
// 62.031 us; speedup vs baseline: 6.8019x; 6.8019x over previous
//
#include <hip/hip_runtime.h>

#define EPSLN 1e-5f

typedef short bf16x8 __attribute__((ext_vector_type(8)));
typedef float f32x4 __attribute__((ext_vector_type(4)));
typedef unsigned short u16;
typedef unsigned short u16x8 __attribute__((ext_vector_type(8)));

__device__ __forceinline__ float wsum(float v){
  #pragma unroll
  for(int o=32;o;o>>=1) v += __shfl_xor(v,o);
  return v;
}
__device__ __forceinline__ float wmax(float v){
  #pragma unroll
  for(int o=32;o;o>>=1) v = fmaxf(v,__shfl_xor(v,o));
  return v;
}
__device__ __forceinline__ u16 f2bf(float f){
  unsigned int u = __float_as_uint(f);
  u = (u + 0x7FFFu + ((u>>16)&1u)) >> 16;
  return (u16)u;
}
__device__ __forceinline__ float bf2f(u16 h){
  return __uint_as_float(((unsigned int)h)<<16);
}

// A: eighth-row per thread. Blocks 0..15 also pack W2 into bf16 B-frag order.
__global__ void __launch_bounds__(256) kA(
                   const float* __restrict__ xin, const float* __restrict__ p,
                   const float* __restrict__ W2,
                   float* __restrict__ xe, float* __restrict__ xa,
                   float* __restrict__ Sv, float* __restrict__ SSv,
                   u16* __restrict__ xinb, u16* __restrict__ phi, u16* __restrict__ plo,
                   u16* __restrict__ w2B){
  int t = threadIdx.x;
  int rl = t>>3, q = t&7;
  int row = blockIdx.x*32 + rl;
  const float4* xr = (const float4*)(xin + row*64 + q*8);
  const float4* pr = (const float4*)(p   + row*64 + q*8);
  float s1=0.f,s2=0.f,s3=0.f,s4=0.f;
  u16x8 xb, ph, pl;
  #pragma unroll
  for(int k=0;k<2;k++){
    float4 xv = xr[k];
    float4 pv = pr[k];
    s1 += xv.x+xv.y+xv.z+xv.w;
    s2 += fabsf(xv.x)+fabsf(xv.y)+fabsf(xv.z)+fabsf(xv.w);
    s3 += pv.x+pv.y+pv.z+pv.w;
    s4 += pv.x*pv.x+pv.y*pv.y+pv.z*pv.z+pv.w*pv.w;
    int o = k*4;
    xb[o+0]=f2bf(xv.x); xb[o+1]=f2bf(xv.y); xb[o+2]=f2bf(xv.z); xb[o+3]=f2bf(xv.w);
    u16 h0=f2bf(pv.x), h1=f2bf(pv.y), h2=f2bf(pv.z), h3=f2bf(pv.w);
    ph[o+0]=h0; ph[o+1]=h1; ph[o+2]=h2; ph[o+3]=h3;
    pl[o+0]=f2bf(pv.x-bf2f(h0)); pl[o+1]=f2bf(pv.y-bf2f(h1));
    pl[o+2]=f2bf(pv.z-bf2f(h2)); pl[o+3]=f2bf(pv.w-bf2f(h3));
  }
  *(u16x8*)(xinb + row*64 + q*8) = xb;
  *(u16x8*)(phi  + row*64 + q*8) = ph;
  *(u16x8*)(plo  + row*64 + q*8) = pl;
  s1 += __shfl_xor(s1,1); s1 += __shfl_xor(s1,2); s1 += __shfl_xor(s1,4);
  s2 += __shfl_xor(s2,1); s2 += __shfl_xor(s2,2); s2 += __shfl_xor(s2,4);
  s3 += __shfl_xor(s3,1); s3 += __shfl_xor(s3,2); s3 += __shfl_xor(s3,4);
  s4 += __shfl_xor(s4,1); s4 += __shfl_xor(s4,2); s4 += __shfl_xor(s4,4);
  if(q==0){ xe[row]=s1*(1.f/64.f); xa[row]=s2*(1.f/64.f); Sv[row]=s3; SSv[row]=s4; }
  if(blockIdx.x<16){
    int j = blockIdx.x;
    for(int idx=threadIdx.x; idx<4096; idx+=256){
      int f = idx>>6, o = idx&63;
      float v = W2[j*4096 + idx];
      int ks = f>>5, kb = (f>>3)&3, i = f&7;
      int nt = o>>4, col = o&15;
      int ln = kb*16 + col;
      w2B[((j*2+ks)*4 + nt)*512 + ln*8 + i] = f2bf(v);
    }
  }
}

// BE: fused kB (blocks 0..127) + kE2 gram MFMA (blocks 128..1151). 32KB LDS union.
__global__ void __launch_bounds__(256) kBE(
                   const float* __restrict__ xe, const float* __restrict__ sw,
                   const float* __restrict__ bs, const float* __restrict__ om,
                   const float* __restrict__ xa, const float* __restrict__ tau,
                   const float* __restrict__ temp,
                   float* __restrict__ er2, float* __restrict__ mask,
                   float* __restrict__ cc,
                   const u16* __restrict__ phi, const u16* __restrict__ plo,
                   float* __restrict__ G){
  __shared__ __align__(16) unsigned char shm[32768];
  int tid = threadIdx.x;
  if(blockIdx.x < 128){
    // ---- kB body ----
    float* swL = (float*)shm;
    float* bsL = swL + 1072;
    float* omL = bsL + 16;
    float* red = omL + 16;
    float* redE= red + 4;              // [16][4]
    int bi = blockIdx.x;
    int i = bi & 15;
    int w = tid>>6, lane = tid&63;
    for(int k=tid;k<16*67;k+=256) swL[k] = sw[i*16*67 + k];
    if(tid<16){ bsL[tid]=bs[i*16+tid]; omL[tid]=fabsf(om[i*16+tid]); }
    float v = xe[bi*256+tid];
    float m = wmax(fabsf(v));
    if(lane==0) red[w]=m;
    __syncthreads();
    m = fmaxf(fmaxf(red[0],red[1]),fmaxf(red[2],red[3]));
    float xn = v/(m+1e-8f);
    xn = fminf(fmaxf(xn,-0.99f),0.99f);
    float sil = xn/(1.f+expf(-xn));
    float vv = (xn+1.f)*33.f;
    int c0 = (int)floorf(vv)-1;
    float acc[16];
    #pragma unroll
    for(int j=0;j<16;j++) acc[j]=0.f;
    #pragma unroll
    for(int k=0;k<4;k++){
      int c = c0+k;
      if(c<0||c>66) continue;
      float d = fabsf(vv-(float)c);
      float bas = d<1.f ? (2.f/3.f - d*d + d*d*d*0.5f)
                : (d<2.f ? (2.f-d)*(2.f-d)*(2.f-d)*(1.f/6.f) : 0.f);
      #pragma unroll
      for(int j=0;j<16;j++) acc[j] += bas*swL[j*67+c];
    }
    float xav = xa[bi*256+tid];
    #pragma unroll
    for(int j=0;j<16;j++){
      float ev = sil*bsL[j] + acc[j] + omL[j];
      er2[(bi*16+j)*256+tid] = ev;
      float pe = wsum(fabsf(ev)*xav);
      if(lane==0) redE[j*4+w]=pe;
    }
    __syncthreads();
    if(tid<16){
      float e = (redE[tid*4+0]+redE[tid*4+1]+redE[tid*4+2]+redE[tid*4+3])*(1.f/256.f);
      float tv = fabsf(temp[0])+1e-4f;
      float ta = fabsf(tau[i*16+tid]);
      float mk = 1.f/(1.f+expf(-(e-ta)/tv));
      mask[bi*16+tid]=mk;
      cc[bi*16+tid]= e/(ta+1e-8f)*mk;
    }
  } else {
    // ---- kE2 body ----
    u16* AfB = (u16*)shm;
    u16* BfB = AfB + 8192;
    int e = blockIdx.x - 128;
    int b = e&7, m = (e>>3)&7, sx = (e>>6)&3, ty = e>>8;  // b lowest -> XCD=b
    int bm = b*8+m;
    int s0 = sx*64, t0 = ty*64;
    int row = tid>>2, dseg = tid&3;
    size_t offA = ((size_t)(b*16+m  )*256 + s0 + row)*64 + dseg*16;
    size_t offB = ((size_t)(b*16+m+8)*256 + t0 + row)*64 + dseg*16;
    int d0 = dseg*16;
    int ks0 = d0>>5, kb0 = (d0>>3)&3;
    int ks1 = (d0+8)>>5, kb1 = ((d0+8)>>3)&3;
    int lr = row&15, stile = row>>4;
    #define AOFF(h,stl,ks,ln) (((((h)*4+(stl))*2+(ks))*64 + (ln))*8)
    {
      uint4 v0 = *(const uint4*)(phi + offA);
      uint4 v1 = *(const uint4*)(phi + offA + 8);
      *(uint4*)(AfB + AOFF(0,stile,ks0,kb0*16+lr)) = v0;
      *(uint4*)(AfB + AOFF(0,stile,ks1,kb1*16+lr)) = v1;
      uint4 w0 = *(const uint4*)(plo + offA);
      uint4 w1 = *(const uint4*)(plo + offA + 8);
      *(uint4*)(AfB + AOFF(1,stile,ks0,kb0*16+lr)) = w0;
      *(uint4*)(AfB + AOFF(1,stile,ks1,kb1*16+lr)) = w1;
      uint4 x0 = *(const uint4*)(phi + offB);
      uint4 x1 = *(const uint4*)(phi + offB + 8);
      *(uint4*)(BfB + AOFF(0,stile,ks0,kb0*16+lr)) = x0;
      *(uint4*)(BfB + AOFF(0,stile,ks1,kb1*16+lr)) = x1;
      uint4 y0 = *(const uint4*)(plo + offB);
      uint4 y1 = *(const uint4*)(plo + offB + 8);
      *(uint4*)(BfB + AOFF(1,stile,ks0,kb0*16+lr)) = y0;
      *(uint4*)(BfB + AOFF(1,stile,ks1,kb1*16+lr)) = y1;
    }
    __syncthreads();
    int w = tid>>6, lane = tid&63;
    bf16x8 ah0 = *(const bf16x8*)(AfB + AOFF(0,w,0,lane));
    bf16x8 ah1 = *(const bf16x8*)(AfB + AOFF(0,w,1,lane));
    bf16x8 al0 = *(const bf16x8*)(AfB + AOFF(1,w,0,lane));
    bf16x8 al1 = *(const bf16x8*)(AfB + AOFF(1,w,1,lane));
    f32x4 acc[4];
    #pragma unroll
    for(int tt=0;tt<4;tt++) acc[tt] = (f32x4){0.f,0.f,0.f,0.f};
    #pragma unroll
    for(int tt=0;tt<4;tt++){
      bf16x8 bh0 = *(const bf16x8*)(BfB + AOFF(0,tt,0,lane));
      bf16x8 bh1 = *(const bf16x8*)(BfB + AOFF(0,tt,1,lane));
      bf16x8 bl0 = *(const bf16x8*)(BfB + AOFF(1,tt,0,lane));
      bf16x8 bl1 = *(const bf16x8*)(BfB + AOFF(1,tt,1,lane));
      acc[tt] = __builtin_amdgcn_mfma_f32_16x16x32_bf16(ah0, bh0, acc[tt], 0,0,0);
      acc[tt] = __builtin_amdgcn_mfma_f32_16x16x32_bf16(ah1, bh1, acc[tt], 0,0,0);
      acc[tt] = __builtin_amdgcn_mfma_f32_16x16x32_bf16(ah0, bl0, acc[tt], 0,0,0);
      acc[tt] = __builtin_amdgcn_mfma_f32_16x16x32_bf16(ah1, bl1, acc[tt], 0,0,0);
      acc[tt] = __builtin_amdgcn_mfma_f32_16x16x32_bf16(al0, bh0, acc[tt], 0,0,0);
      acc[tt] = __builtin_amdgcn_mfma_f32_16x16x32_bf16(al1, bh1, acc[tt], 0,0,0);
    }
    int col = lane&15, r4 = lane>>4;
    #pragma unroll
    for(int tt=0;tt<4;tt++){
      #pragma unroll
      for(int r=0;r<4;r++){
        G[((size_t)bm*256 + s0 + w*16 + r4*4 + r)*256 + t0 + tt*16 + col] = acc[tt][r];
      }
    }
    #undef AOFF
  }
}

// D: masked mean (bf16 xin); LN; x' = xn@W2[j] via MFMA; emit xpB, xvb (bf16).
__global__ void __launch_bounds__(256) kD(
                   const u16* __restrict__ xinb, const float* __restrict__ er2,
                   const float* __restrict__ mask, const u16* __restrict__ w2B,
                   const float* __restrict__ lnw, const float* __restrict__ lnb,
                   const float* __restrict__ bp,
                   u16* __restrict__ xoutb, float* __restrict__ xp,
                   u16* __restrict__ xpB){
  int b = blockIdx.x, j = blockIdx.y, st = blockIdx.z;
  int tid = threadIdx.x, w = tid>>6, lane = tid&63;
  __shared__ __align__(16) u16 xnS[16*64];  // bf16, XOR-swizzled
  __shared__ float mcL[16];
  if(tid<16) mcL[tid]=mask[(b*16+tid)*16+j];
  __syncthreads();
  float lw = lnw[j*64+lane], lb = lnb[j*64+lane];
  int bj = b*16+j;
  unsigned char* xnB = (unsigned char*)xnS;
  #pragma unroll
  for(int ri=0;ri<4;ri++){
    int sl = w*4 + ri;
    int s = st*16 + sl;
    float acc=0.f;
    #pragma unroll
    for(int i=0;i<16;i++){
      acc += er2[((b*16+i)*16+j)*256+s]*mcL[i]*bf2f(xinb[((b*16+i)*256+s)*64+lane]);
    }
    float xval = acc*(1.f/16.f);
    xoutb[((size_t)bj*256+s)*64+lane]=f2bf(xval);
    float mu = wsum(xval)*(1.f/64.f);
    float dv = xval-mu;
    float var = wsum(dv*dv)*(1.f/64.f);
    float xnv = dv*rsqrtf(var+EPSLN)*lw + lb;
    *(u16*)(xnB + ((sl*128 + lane*2) ^ ((sl&7)<<4))) = f2bf(xnv);
  }
  __syncthreads();
  f32x4 acc = {0.f,0.f,0.f,0.f};
  int m = lane&15, kb = lane>>4;
  #pragma unroll
  for(int ks=0;ks<2;ks++){
    bf16x8 a = *(const bf16x8*)(xnB + ((m*128 + ks*64 + kb*16) ^ ((m&7)<<4)));
    bf16x8 bfr = *(const bf16x8*)(w2B + ((j*2+ks)*4 + w)*512 + lane*8);
    acc = __builtin_amdgcn_mfma_f32_16x16x32_bf16(a, bfr, acc, 0, 0, 0);
  }
  int f = w*16 + m;
  u16 pk[4];
  #pragma unroll
  for(int r=0;r<4;r++){
    int si = kb*4 + r;
    int s = st*16 + si;
    float xpr = acc[r] + bp[((size_t)j*256+s)*64+f];
    xp[((size_t)bj*256+s)*64+f] = xpr;
    pk[r] = f2bf(xpr);
  }
  int s0 = st*16 + kb*4;
  int flat = ((s0>>5)*4 + w)*512 + ((s0>>3)&3)*128 + m*8 + (s0&7);
  *(ushort4*)(xpB + (size_t)bj*16384 + flat) = *(ushort4*)pk;
}

// F: 2 j per block; inline LN stats; defer-max softmax (LN rows bound |raw|<=22.6);
//    MFMA AV; conv via LDS-staged xp window; residuals. b in blockIdx.x -> XCD=b.
__global__ void __launch_bounds__(256) kF(
    const float* __restrict__ G, const float* __restrict__ cc,
    const float* __restrict__ Sv, const float* __restrict__ SSv,
    const float* __restrict__ xp, const u16* __restrict__ xpB,
    const float* __restrict__ cw,
    const u16* __restrict__ xarrb, const float* __restrict__ temp,
    const float* __restrict__ alpha, const float* __restrict__ beta,
    const float* __restrict__ gamma_, const float* __restrict__ theta,
    float* __restrict__ out){
  int b = blockIdx.x, jp = blockIdx.y, st = blockIdx.z;
  int j0 = jp*2, j1 = j0+1;
  int tid = threadIdx.x, w = tid>>6, lane = tid&63;
  __shared__ __align__(16) unsigned char ovl[26112];     // probS (16KB) / xpT (25.5KB)
  __shared__ float mKL[2][256], rKL[2][256];
  __shared__ __align__(16) float mQL[2][256], rQL[2][256];
  unsigned char* prB0 = ovl;
  unsigned char* prB1 = ovl + 8192;
  float* xpT = (float*)ovl;                              // [2][3][16][68]
  float tv = fabsf(temp[0])+1e-4f;
  float inv = 1.f/(sqrtf(512.f)*tv);
  float ck0[8],cq0[8],ck1[8],cq1[8],aM0[8],aM1[8];
  #pragma unroll
  for(int m=0;m<8;m++){
    ck0[m]=cc[(b*16+m)*16+j0];  cq0[m]=cc[(b*16+m+8)*16+j0];
    ck1[m]=cc[(b*16+m)*16+j1];  cq1[m]=cc[(b*16+m+8)*16+j1];
    aM0[m]=ck0[m]*cq0[m];       aM1[m]=ck1[m]*cq1[m];
  }
  {
    int t = tid;
    float sk0=0,ssk0=0,sq0=0,ssq0=0,sk1=0,ssk1=0,sq1=0,ssq1=0;
    #pragma unroll
    for(int m=0;m<8;m++){
      float svk = Sv [(b*16+m)*256+t];
      float ssvk= SSv[(b*16+m)*256+t];
      float svq = Sv [(b*16+m+8)*256+t];
      float ssvq= SSv[(b*16+m+8)*256+t];
      sk0 += ck0[m]*svk;  ssk0 += ck0[m]*ck0[m]*ssvk;
      sq0 += cq0[m]*svq;  ssq0 += cq0[m]*cq0[m]*ssvq;
      sk1 += ck1[m]*svk;  ssk1 += ck1[m]*ck1[m]*ssvk;
      sq1 += cq1[m]*svq;  ssq1 += cq1[m]*cq1[m]*ssvq;
    }
    float mk0 = sk0*(1.f/512.f), mk1 = sk1*(1.f/512.f);
    float mq0 = sq0*(1.f/512.f), mq1 = sq1*(1.f/512.f);
    mKL[0][t]=mk0; rKL[0][t]=rsqrtf(ssk0*(1.f/512.f)-mk0*mk0+EPSLN);
    mKL[1][t]=mk1; rKL[1][t]=rsqrtf(ssk1*(1.f/512.f)-mk1*mk1+EPSLN);
    mQL[0][t]=mq0; rQL[0][t]=rsqrtf(ssq0*(1.f/512.f)-mq0*mq0+EPSLN);
    mQL[1][t]=mq1; rQL[1][t]=rsqrtf(ssq1*(1.f/512.f)-mq1*mq1+EPSLN);
  }
  __syncthreads();
  int bj0 = b*16+j0, bj1 = b*16+j1;
  const float* Gb = G + (size_t)(b*8)*65536;
  float4 mQ40 = *(const float4*)&mQL[0][lane*4];
  float4 rQ40 = *(const float4*)&rQL[0][lane*4];
  float4 mQ41 = *(const float4*)&mQL[1][lane*4];
  float4 rQ41 = *(const float4*)&rQL[1][lane*4];
  #pragma unroll
  for(int q=0;q<4;q++){
    int si = w*4+q;
    int s = st*16 + si;
    f32x4 dot0 = {0.f,0.f,0.f,0.f}, dot1 = {0.f,0.f,0.f,0.f};
    #pragma unroll
    for(int m=0;m<8;m++){
      f32x4 g4 = *(const f32x4*)(Gb + (size_t)m*65536 + s*256 + lane*4);
      dot0 += aM0[m]*g4;     // vector op -> v_pk_fma_f32 pairs
      dot1 += aM1[m]*g4;
    }
    // defer-max: LN'd rows => |raw| <= sqrt(512)/tv ~ 22.6, exp safe without max-sub
    {
      float mKs = 512.f*mKL[0][s], rKs = rKL[0][s];
      float e0 = expf((dot0[0] - mKs*mQ40.x)*rKs*rQ40.x*inv);
      float e1 = expf((dot0[1] - mKs*mQ40.y)*rKs*rQ40.y*inv);
      float e2 = expf((dot0[2] - mKs*mQ40.z)*rKs*rQ40.z*inv);
      float e3 = expf((dot0[3] - mKs*mQ40.w)*rKs*rQ40.w*inv);
      float isf = 1.f/wsum(e0+e1+e2+e3);
      u16 pk[4] = {f2bf(e0*isf), f2bf(e1*isf), f2bf(e2*isf), f2bf(e3*isf)};
      *(ushort4*)(prB0 + ((si*512 + lane*8) ^ ((si&7)<<4))) = *(ushort4*)pk;
    }
    {
      float mKs = 512.f*mKL[1][s], rKs = rKL[1][s];
      float e0 = expf((dot1[0] - mKs*mQ41.x)*rKs*rQ41.x*inv);
      float e1 = expf((dot1[1] - mKs*mQ41.y)*rKs*rQ41.y*inv);
      float e2 = expf((dot1[2] - mKs*mQ41.z)*rKs*rQ41.z*inv);
      float e3 = expf((dot1[3] - mKs*mQ41.w)*rKs*rQ41.w*inv);
      float isf = 1.f/wsum(e0+e1+e2+e3);
      u16 pk[4] = {f2bf(e0*isf), f2bf(e1*isf), f2bf(e2*isf), f2bf(e3*isf)};
      *(ushort4*)(prB1 + ((si*512 + lane*8) ^ ((si&7)<<4))) = *(ushort4*)pk;
    }
  }
  __syncthreads();
  int m_ = lane&15, kb = lane>>4;
  f32x4 acc0 = {0.f,0.f,0.f,0.f}, acc1 = {0.f,0.f,0.f,0.f};
  const u16* xpB0 = xpB + (size_t)bj0*16384;
  const u16* xpB1 = xpB + (size_t)bj1*16384;
  #pragma unroll
  for(int ks=0;ks<8;ks++){
    int aoff = (m_*512 + ks*64 + kb*16) ^ ((m_&7)<<4);
    int boff = ((ks*4 + w)*64 + lane)*8;
    bf16x8 a0 = *(const bf16x8*)(prB0 + aoff);
    bf16x8 a1 = *(const bf16x8*)(prB1 + aoff);
    acc0 = __builtin_amdgcn_mfma_f32_16x16x32_bf16(a0, *(const bf16x8*)(xpB0 + boff), acc0, 0,0,0);
    acc1 = __builtin_amdgcn_mfma_f32_16x16x32_bf16(a1, *(const bf16x8*)(xpB1 + boff), acc1, 0,0,0);
  }
  __syncthreads();   // prB reads done; overlay xpT
  for(int idx4 = tid; idx4 < 1536; idx4 += 256){
    int jj = idx4 / 768;
    int rem = idx4 - jj*768;
    int rr_i = rem >> 8;
    int pos = rem & 255;
    int ci = pos>>4, f4 = pos&15;
    int grow = st - 1 + rr_i;
    float4 v = {0.f,0.f,0.f,0.f};
    if(grow>=0 && grow<16){
      v = *(const float4*)(xp + ((size_t)(b*16+j0+jj)*256 + grow*16 + ci)*64 + f4*4);
    }
    *(float4*)(xpT + ((jj*3+rr_i)*16+ci)*68 + f4*4) = v;
  }
  __syncthreads();
  int f = w*16 + m_;
  #pragma unroll
  for(int jj=0;jj<2;jj++){
    int j = j0+jj;
    int bj = b*16+j;
    f32x4 acc = jj ? acc1 : acc0;
    float al = fabsf(alpha[j]), be=fabsf(beta[j]), th=fabsf(theta[j]), ga=gamma_[j];
    const float* wq = cw + (j*64+f)*9;
    float w0=wq[0],w1=wq[1],w2=wq[2],w3v=wq[3],w4=wq[4],w5=wq[5],w6=wq[6],w7=wq[7],w8=wq[8];
    #pragma unroll
    for(int r=0;r<4;r++){
      int si = kb*4 + r;
      int s = st*16 + si;
      float gl = acc[r];
      float cv=0.f;
      #pragma unroll
      for(int dr=0;dr<3;dr++){
        float kw0 = dr==0?w0:(dr==1?w3v:w6);
        float kw1 = dr==0?w1:(dr==1?w4:w7);
        float kw2 = dr==0?w2:(dr==1?w5:w8);
        const float* rowp = xpT + ((jj*3+dr)*16)*68;
        if(si>0)  cv += rowp[(si-1)*68+f]*kw0;
                  cv += rowp[(si  )*68+f]*kw1;
        if(si<15) cv += rowp[(si+1)*68+f]*kw2;
      }
      float diag = xpT[((jj*3+1)*16+si)*68+f];
      size_t gi = ((size_t)bj*256+s)*64+f;
      out[gi] = be*gl + al*diag + th*cv + ga*bf2f(xarrb[gi]);
    }
  }
}

extern "C" void kernel_launch(void* const* d_in, const int* in_sizes, int n_in,
                              void* d_out, int out_size, void* d_ws, size_t ws_size,
                              hipStream_t stream) {
  const float* xin = (const float*)d_in[0];
  const float* pxp = (const float*)d_in[1];
  const float* sw  = (const float*)d_in[2];
  const float* bs  = (const float*)d_in[3];
  const float* tau = (const float*)d_in[4];
  const float* temp= (const float*)d_in[5];
  const float* om  = (const float*)d_in[6];
  const float* W2  = (const float*)d_in[7];
  const float* bp  = (const float*)d_in[8];
  const float* lnw = (const float*)d_in[9];
  const float* lnb = (const float*)d_in[10];
  const float* alpha=(const float*)d_in[11];
  const float* beta= (const float*)d_in[12];
  const float* gam = (const float*)d_in[13];
  const float* theta=(const float*)d_in[14];
  const float* cw  = (const float*)d_in[15];
  float* outp = (float*)d_out;
  float* xpo  = outp + 2097152;   // x_prime = second output

  float* ws  = (float*)d_ws;
  float* xe  = ws;                // 32768
  float* xa  = xe + 32768;        // 32768
  float* Sv  = xa + 32768;        // 32768
  float* SSv = Sv + 32768;        // 32768
  float* er2 = SSv + 32768;       // 524288
  float* mask= er2 + 524288;      // 2048
  float* ccv = mask + 2048;       // 2048
  float* Gv  = ccv + 2048;        // 4194304
  u16* xvb = (u16*)(Gv + 4194304);    // 2097152 u16 (bf16 x)
  u16* xpB = xvb + 2097152;           // 2097152 u16
  u16* w2B = xpB + 2097152;           // 65536 u16
  u16* xinb= w2B + 65536;             // 2097152 u16
  u16* phi = xinb + 2097152;          // 2097152 u16
  u16* plo = phi + 2097152;           // 2097152 u16

  kA<<<1024,256,0,stream>>>(xin,pxp,W2,xe,xa,Sv,SSv,xinb,phi,plo,w2B);
  kBE<<<1152,256,0,stream>>>(xe,sw,bs,om,xa,tau,temp,er2,mask,ccv,phi,plo,Gv);
  kD<<<dim3(8,16,16),256,0,stream>>>(xinb,er2,mask,w2B,lnw,lnb,bp,xvb,xpo,xpB);
  kF<<<dim3(8,8,16),256,0,stream>>>(Gv,ccv,Sv,SSv,xpo,xpB,cw,xvb,temp,
                                    alpha,beta,gam,theta,outp);
}